// Round 13
// baseline (31.474 us; speedup 1.0000x reference)
//
#include <hip/hip_runtime.h>
#include <math.h>

#define B_ 16
#define T_ 2048
#define N_ 8
#define D_ 512
#define DTW 4           // d-tiles (of 16) per wave
#define LPAD 520        // LDS row pitch (words)

// -2*pi/2048
#define NEG_W0 (-3.0679615757712823e-3f)
// -2*pi/32
#define NEG_W32 (-0.19634954084936207f)
// -2*pi/1024
#define NEG_W1024 (-6.1359231515425647e-3f)
// -2*ln(10000)/512
#define NEG_LDIV (-0.035977892078031555f)

typedef __attribute__((ext_vector_type(8))) short bf16x8;
typedef __attribute__((ext_vector_type(4))) float f32x4;

// fp32 -> bf16 (round-to-nearest-even)
static __device__ __forceinline__ short f2bf(float f) {
  unsigned int u = __float_as_uint(f);
  unsigned int r = u + 0x7FFFu + ((u >> 16) & 1u);
  return (short)(r >> 16);
}

// ws layout (byte offsets): [0,4096) pmax[256]+nyqS[128];
// [4K,4K+4M) FET tab f32[2048][512]; amat bf16[512][32] (32 KB);
// xbf bf16[16][2048][8] (512 KB); cnt bf16[16][2048][8] (512 KB).
// All rewritten unconditionally every call (no init/protocol hazards).

// ---- prep: 305 blocks x 1024 thr (single dispatch round).
//  blk 0..255 : folded radix-32 FFT per (bn,parity) -> pmax/nyqS
//  blk 256..287: xbf (x cast to bf16 rows) + cnt (mark-count bf16x8 rows)
//  blk 288    : amat (A-matrix: conv slots 0..23, temporal 24..30, 31=0)
//  blk 289..304: FET tabgen by rotation — 128 t-strips x 128 d-quads =
//                16384 threads = 16 blocks (R12 bug: 32 blocks overflowed
//                the 4MB tab region and scribbled amat/xbf/cnt -> NaN)
__global__ __launch_bounds__(1024) void prep_kernel(
    const float* __restrict__ x, const int* __restrict__ xmark,
    const float* __restrict__ convw, float* __restrict__ pmax,
    float* __restrict__ nyqS, float* __restrict__ tab,
    short* __restrict__ amat, short* __restrict__ xbf,
    short* __restrict__ cnt) {
  int tid = threadIdx.x;
  int blk = blockIdx.x;

  if (blk >= 256) {
    int j = blk - 256;
    if (j < 32) {                         // ---- xbf + cnt rows ----
      int r = j * 1024 + tid;             // r = b*T + t, 0..32767
      const float4* xr = (const float4*)(x + (size_t)r * 8);
      float4 lo = xr[0], hi = xr[1];
      bf16x8 v;
      v[0] = f2bf(lo.x); v[1] = f2bf(lo.y); v[2] = f2bf(lo.z); v[3] = f2bf(lo.w);
      v[4] = f2bf(hi.x); v[5] = f2bf(hi.y); v[6] = f2bf(hi.z); v[7] = f2bf(hi.w);
      *(bf16x8*)(xbf + (size_t)r * 8) = v;
      int4 mk = *(const int4*)(xmark + (size_t)r * 4);
      bf16x8 cv;
#pragma unroll
      for (int p = 0; p < 8; ++p) {
        int cc = (mk.x == p) + (mk.y == p) + (mk.z == p) + (mk.w == p);
        cv[p] = f2bf((float)cc);
      }
      *(bf16x8*)(cnt + (size_t)r * 8) = cv;
    } else if (j == 32) {                 // ---- amat builder ----
      if (tid < 512) {
        int d = tid;
        short row[32];
#pragma unroll
        for (int kk = 0; kk < 24; ++kk) {
          int g = kk >> 3, n = kk & 7;    // A[d][g*8+n] = W[d][n][k=g]
          row[kk] = f2bf(convw[d * 24 + n * 3 + g]);
        }
        float divv = expf((float)(d >> 1) * NEG_LDIV);
        float s1, c1;
        sincosf(divv, &s1, &c1);
        int odd = d & 1;
        row[24] = f2bf(odd ? 1.f : 0.f);
        float ps = s1, pc = c1;
        row[25] = f2bf(odd ? pc : ps);
#pragma unroll
        for (int p = 2; p < 7; ++p) {
          float ns = fmaf(ps, c1, pc * s1);
          float nc = fmaf(pc, c1, -ps * s1);
          ps = ns; pc = nc;
          row[24 + p] = f2bf(odd ? pc : ps);
        }
        row[31] = 0;                      // marks < 7
#pragma unroll
        for (int q = 0; q < 4; ++q)
          *(bf16x8*)(amat + d * 32 + q * 8) = *(bf16x8*)&row[q * 8];
      }
    } else {                              // ---- FET tabgen by rotation ----
      int gt = (j - 33) * 1024 + tid;     // 0..16383
      int tb = gt >> 7;                   // 16-row t-strip, 0..127
      int d4 = gt & 127;                  // float4 column (d-pairs 2*d4, 2*d4+1)
      float dv0 = expf((float)(d4 * 2) * NEG_LDIV);
      float dv1 = expf((float)(d4 * 2 + 1) * NEG_LDIV);
      float tf = (float)(tb * 16);
      float s0, c0, s1, c1, r0s, r0c, r1s, r1c;
      sincosf(tf * dv0, &s0, &c0);
      sincosf(tf * dv1, &s1, &c1);
      sincosf(dv0, &r0s, &r0c);           // small-arg fast path
      sincosf(dv1, &r1s, &r1c);
      float* row = tab + (size_t)(tb * 16) * D_ + d4 * 4;
#pragma unroll
      for (int u = 0; u < 16; ++u) {
        f32x4 v; v[0] = s0; v[1] = c0; v[2] = s1; v[3] = c1;
        *(f32x4*)row = v;
        row += D_;
        float ns0 = fmaf(s0, r0c, c0 * r0s), nc0 = fmaf(c0, r0c, -s0 * r0s);
        s0 = ns0; c0 = nc0;
        float ns1 = fmaf(s1, r1c, c1 * r1s), nc1 = fmaf(c1, r1c, -s1 * r1s);
        s1 = ns1; c1 = nc1;
      }
    }
    return;
  }

  // ---- folded radix-32 FFT (unchanged, validated R4..R11) ----
  __shared__ __align__(16) float2 ybuf[1024];
  __shared__ __align__(16) float2 Bl[1024];
  __shared__ __align__(16) float2 part[1024];
  __shared__ float swav[16];
  __shared__ float pwav[8];
  int bn = blk >> 1, parity = blk & 1;
  int b = bn >> 3, n = bn & 7;
  const float* xb = x + (size_t)b * (T_ * N_) + n;

  float va = xb[tid * 8];
  float vb = xb[(tid + 1024) * 8];
  float ea = va + vb;
  float sgn = (tid & 1) ? -ea : ea;       // Nyquist partial (-1)^t e_t
#pragma unroll
  for (int off = 32; off > 0; off >>= 1) sgn += __shfl_down(sgn, off);
  if ((tid & 63) == 0) swav[tid >> 6] = sgn;

  if (parity == 0) {
    ((float*)ybuf)[tid] = ea;
  } else {
    float o = va - vb;
    float c0, s0;
    sincosf((float)tid * NEG_W0, &s0, &c0);
    ybuf[tid] = make_float2(o * c0, o * s0);
  }
  __syncthreads();

  int m0 = tid & 31, t0 = tid >> 5;
  float d1 = (float)m0 * NEG_W32;
  float K1 = 2.0f * cosf(d1);
  float c = 1.f, s = 0.f, cp, sp;
  sincosf(-d1, &sp, &cp);
  float ar = 0.f, ai = 0.f;
  if (parity == 0) {
    const float* ya = (const float*)ybuf;
#pragma unroll 8
    for (int t1 = 0; t1 < 32; ++t1) {
      float y = ya[t1 * 32 + t0];
      ar = fmaf(y, c, ar); ai = fmaf(y, s, ai);
      float nc = fmaf(K1, c, -cp), ns = fmaf(K1, s, -sp);
      cp = c; sp = s; c = nc; s = ns;
    }
  } else {
#pragma unroll 8
    for (int t1 = 0; t1 < 32; ++t1) {
      float2 y = ybuf[t1 * 32 + t0];
      ar = fmaf(y.x, c, fmaf(-y.y, s, ar));
      ai = fmaf(y.x, s, fmaf(y.y, c, ai));
      float nc = fmaf(K1, c, -cp), ns = fmaf(K1, s, -sp);
      cp = c; sp = s; c = nc; s = ns;
    }
  }
  {
    float ct, st;
    sincosf((float)(t0 * m0) * NEG_W1024, &st, &ct);
    Bl[t0 * 32 + m0] = make_float2(ar * ct - ai * st, fmaf(ar, st, ai * ct));
  }
  __syncthreads();

  int m02 = tid & 31;
  int m1 = (tid >> 5) & 15;
  int h = tid >> 9;
  float d2 = (float)m1 * NEG_W32;
  float K2 = 2.0f * cosf(d2);
  int t0s = h * 16;
  float c2, s2, c2p, s2p;
  sincosf((float)t0s * d2, &s2, &c2);
  sincosf((float)(t0s - 1) * d2, &s2p, &c2p);
  float yr = 0.f, yi = 0.f;
#pragma unroll 8
  for (int jj = 0; jj < 16; ++jj) {
    float2 bv = Bl[(t0s + jj) * 32 + m02];
    yr = fmaf(bv.x, c2, fmaf(-bv.y, s2, yr));
    yi = fmaf(bv.x, s2, fmaf(bv.y, c2, yi));
    float nc = fmaf(K2, c2, -c2p), ns = fmaf(K2, s2, -s2p);
    c2p = c2; s2p = s2; c2 = nc; s2 = ns;
  }
  part[tid] = make_float2(yr, yi);
  __syncthreads();
  if (tid < 512) {
    float2 pa = part[tid], pb = part[tid + 512];
    float rr = pa.x + pb.x, ii = pa.y + pb.y;
    float P = fmaf(rr, rr, ii * ii);
#pragma unroll
    for (int off = 32; off > 0; off >>= 1) P = fmaxf(P, __shfl_down(P, off));
    if ((tid & 63) == 0) pwav[tid >> 6] = P;
  }
  __syncthreads();
  if (tid < 64) {
    float mxv = (tid < 8) ? pwav[tid] : 0.f;
    float svv = (tid < 16) ? swav[tid] : 0.f;
#pragma unroll
    for (int off = 8; off > 0; off >>= 1) {
      mxv = fmaxf(mxv, __shfl_down(mxv, off));
      svv += __shfl_down(svv, off);
    }
    if (tid == 0) {
      pmax[blk] = mxv;                    // unconditional plain store
      if (parity == 0) nyqS[bn] = svv;
    }
  }
}

// ---- main: one (batch, 16-row t-tile) per block, grid 2048. MFMA (conv
// slots 0..23 + temporal 24..31) -> LDS repack -> one barrier -> 4 x 8 KB
// perfectly sequential store rounds. 3 blocks/CU (24 waves) via low VGPR.
__global__ __launch_bounds__(512, 6) void main_kernel(
    const short* __restrict__ amat, const short* __restrict__ xbf,
    const short* __restrict__ cnt, const float* __restrict__ tab,
    const float* __restrict__ pmax, const float* __restrict__ nyqS,
    float* __restrict__ out) {
  __shared__ __align__(16) float lds[16 * LPAD];
  int tid = threadIdx.x;
  int lane = tid & 63;
  int w = tid >> 6;            // wave -> d in [w*64, w*64+64)
  int c = lane & 15;           // t-col / A d-row
  int g = lane >> 4;           // k-slot group / C d-subgroup
  int blk = blockIdx.x;
  int b = blk >> 7;
  int t0 = (blk & 127) * 16;

  // w1/w0 (wave-uniform scalar loads, L2-hot)
  int m = 0;
#pragma unroll
  for (int nn = 0; nn < 8; ++nn) {
    int bn = b * 8 + nn;
    float mx = fmaxf(pmax[2 * bn], pmax[2 * bn + 1]);
    float S = nyqS[bn];
    if (S * S > mx) ++m;
  }
  float w1 = (float)(8 - m) * 0.125f;
  float w0 = (float)m * 0.125f;

  bf16x8 afrag[DTW];
  f32x4 fet[DTW];
#pragma unroll
  for (int q = 0; q < DTW; ++q) {
    int d0 = (w * DTW + q) * 16;
    afrag[q] = *(const bf16x8*)(amat + (size_t)(d0 + c) * 32 + g * 8);
    fet[q] = *(const f32x4*)(tab + (size_t)(t0 + c) * D_ + d0 + g * 4);
  }

  bf16x8 bfrag;
  if (g < 3) {
    int row = (t0 + c + g - 1) & (T_ - 1);      // circular pad
    bfrag = *(const bf16x8*)(xbf + ((size_t)b * T_ + row) * 8);
  } else {
    bfrag = *(const bf16x8*)(cnt + ((size_t)b * T_ + t0 + c) * 8);
  }

  const f32x4 zac = {0.f, 0.f, 0.f, 0.f};
#pragma unroll
  for (int q = 0; q < DTW; ++q) {
    f32x4 acc = __builtin_amdgcn_mfma_f32_16x16x32_bf16(
        afrag[q], bfrag, zac, 0, 0, 0);
    f32x4 ov;
    ov[0] = fmaf(w1, fet[q][0], acc[0]);
    ov[1] = fmaf(w1, fet[q][1], acc[1]) + w0;
    ov[2] = fmaf(w1, fet[q][2], acc[2]);
    ov[3] = fmaf(w1, fet[q][3], acc[3]) + w0;
    int d0 = (w * DTW + q) * 16;
    *(f32x4*)(lds + c * LPAD + d0 + g * 4) = ov;
  }
  __syncthreads();
  // stream the 16x512 tile out as 4 x 8KB perfectly sequential rounds
  float* obase = out + ((size_t)b * T_ + t0) * D_;
#pragma unroll
  for (int r = 0; r < 4; ++r) {
    int e = r * 2048 + tid * 4;                 // element offset in tile
    int trow = e >> 9, col = e & 511;
    f32x4 v = *(const f32x4*)(lds + trow * LPAD + col);
    *(f32x4*)(obase + e) = v;
  }
}

extern "C" void kernel_launch(void* const* d_in, const int* in_sizes, int n_in,
                              void* d_out, int out_size, void* d_ws, size_t ws_size,
                              hipStream_t stream) {
  const float* x = (const float*)d_in[0];
  const int* xmark = (const int*)d_in[1];
  const float* convw = (const float*)d_in[2];
  float* out = (float*)d_out;

  char* ws = (char*)d_ws;
  float* pmax = (float*)ws;                            // 256 f
  float* nyqS = pmax + 256;                            // 128 f
  float* tab = (float*)(ws + 4096);                    // 4 MB FET
  short* amat = (short*)(ws + 4096 + 4194304);         // 32 KB
  short* xbf = (short*)(ws + 4096 + 4194304 + 32768);  // 512 KB
  short* cnt = (short*)(ws + 4096 + 4194304 + 32768 + 524288);  // 512 KB

  prep_kernel<<<305, 1024, 0, stream>>>(x, xmark, convw, pmax, nyqS, tab,
                                        amat, xbf, cnt);
  main_kernel<<<B_ * (T_ / 16), 512, 0, stream>>>(amat, xbf, cnt, tab,
                                                  pmax, nyqS, out);
}

// Round 14
// 29.833 us; speedup vs baseline: 1.0550x; 1.0550x over previous
//
#include <hip/hip_runtime.h>
#include <math.h>

#define B_ 16
#define T_ 2048
#define N_ 8
#define D_ 512
#define DTW 4           // d-tiles (of 16) per wave
#define LPAD 520        // LDS row pitch (words)

// -2*pi/2048
#define NEG_W0 (-3.0679615757712823e-3f)
// -2*pi/32
#define NEG_W32 (-0.19634954084936207f)
// -2*pi/1024
#define NEG_W1024 (-6.1359231515425647e-3f)
// -2*ln(10000)/512
#define NEG_LDIV (-0.035977892078031555f)

typedef __attribute__((ext_vector_type(8))) short bf16x8;
typedef __attribute__((ext_vector_type(4))) float f32x4;

// fp32 -> bf16 (round-to-nearest-even)
static __device__ __forceinline__ short f2bf(float f) {
  unsigned int u = __float_as_uint(f);
  unsigned int r = u + 0x7FFFu + ((u >> 16) & 1u);
  return (short)(r >> 16);
}

// ws layout (byte offsets): [0,4096) pmax[512]+nyqS[128];
// [4K,4K+4M) FET tab f32[2048][512]; amat bf16[512][32] (32 KB);
// xbf bf16[16][2048][8] (512 KB); cnt bf16[16][2048][8] (512 KB).
// All rewritten unconditionally every call.

// ---- prep: 609 blocks x 512 thr (8-wave blocks, 4/CU resident).
//  blk 0..511 : fft, block = (bn, parity, m1-half). Radix-32 two-stage
//               Cooley-Tukey of the folded 1024-pt DFT; stage 1 duplicated
//               across sibling half-blocks; stage 2 does 8 m1 values.
//               pmax[blk] = partial max (4 per bn). Nyquist sum from e.
//  blk 512..575: xbf + cnt rows (512 rows/block)
//  blk 576    : amat
//  blk 577..608: FET tabgen by rotation (16-row strips)
__global__ __launch_bounds__(512) void prep_kernel(
    const float* __restrict__ x, const int* __restrict__ xmark,
    const float* __restrict__ convw, float* __restrict__ pmax,
    float* __restrict__ nyqS, float* __restrict__ tab,
    short* __restrict__ amat, short* __restrict__ xbf,
    short* __restrict__ cnt) {
  int tid = threadIdx.x;
  int blk = blockIdx.x;

  if (blk >= 512) {
    int j = blk - 512;
    if (j < 64) {                         // ---- xbf + cnt rows ----
      int r = j * 512 + tid;              // r = b*T + t, 0..32767
      const float4* xr = (const float4*)(x + (size_t)r * 8);
      float4 lo = xr[0], hi = xr[1];
      bf16x8 v;
      v[0] = f2bf(lo.x); v[1] = f2bf(lo.y); v[2] = f2bf(lo.z); v[3] = f2bf(lo.w);
      v[4] = f2bf(hi.x); v[5] = f2bf(hi.y); v[6] = f2bf(hi.z); v[7] = f2bf(hi.w);
      *(bf16x8*)(xbf + (size_t)r * 8) = v;
      int4 mk = *(const int4*)(xmark + (size_t)r * 4);
      bf16x8 cv;
#pragma unroll
      for (int p = 0; p < 8; ++p) {
        int cc = (mk.x == p) + (mk.y == p) + (mk.z == p) + (mk.w == p);
        cv[p] = f2bf((float)cc);
      }
      *(bf16x8*)(cnt + (size_t)r * 8) = cv;
    } else if (j == 64) {                 // ---- amat builder ----
      int d = tid;
      short row[32];
#pragma unroll
      for (int kk = 0; kk < 24; ++kk) {
        int g = kk >> 3, n = kk & 7;      // A[d][g*8+n] = W[d][n][k=g]
        row[kk] = f2bf(convw[d * 24 + n * 3 + g]);
      }
      float divv = expf((float)(d >> 1) * NEG_LDIV);
      float s1, c1;
      sincosf(divv, &s1, &c1);
      int odd = d & 1;
      row[24] = f2bf(odd ? 1.f : 0.f);
      float ps = s1, pc = c1;
      row[25] = f2bf(odd ? pc : ps);
#pragma unroll
      for (int p = 2; p < 7; ++p) {
        float ns = fmaf(ps, c1, pc * s1);
        float nc = fmaf(pc, c1, -ps * s1);
        ps = ns; pc = nc;
        row[24 + p] = f2bf(odd ? pc : ps);
      }
      row[31] = 0;                        // marks < 7
#pragma unroll
      for (int q = 0; q < 4; ++q)
        *(bf16x8*)(amat + d * 32 + q * 8) = *(bf16x8*)&row[q * 8];
    } else {                              // ---- FET tabgen by rotation ----
      int gt = (j - 65) * 512 + tid;      // 0..16383
      int tb = gt >> 7;                   // 16-row t-strip, 0..127
      int d4 = gt & 127;                  // float4 column
      float dv0 = expf((float)(d4 * 2) * NEG_LDIV);
      float dv1 = expf((float)(d4 * 2 + 1) * NEG_LDIV);
      float tf = (float)(tb * 16);
      float s0, c0, s1, c1, r0s, r0c, r1s, r1c;
      sincosf(tf * dv0, &s0, &c0);
      sincosf(tf * dv1, &s1, &c1);
      sincosf(dv0, &r0s, &r0c);
      sincosf(dv1, &r1s, &r1c);
      float* row = tab + (size_t)(tb * 16) * D_ + d4 * 4;
#pragma unroll
      for (int u = 0; u < 16; ++u) {
        f32x4 v; v[0] = s0; v[1] = c0; v[2] = s1; v[3] = c1;
        *(f32x4*)row = v;
        row += D_;
        float ns0 = fmaf(s0, r0c, c0 * r0s), nc0 = fmaf(c0, r0c, -s0 * r0s);
        s0 = ns0; c0 = nc0;
        float ns1 = fmaf(s1, r1c, c1 * r1s), nc1 = fmaf(c1, r1c, -s1 * r1s);
        s1 = ns1; c1 = nc1;
      }
    }
    return;
  }

  // ---- fft: block = (bn, parity, h) ----
  __shared__ __align__(16) float2 ybuf[1024];  // parity0: first half = float[1024]
  __shared__ __align__(16) float2 Bl[1024];
  __shared__ __align__(16) float2 part[512];
  __shared__ float swav[8];
  __shared__ float pwav[4];
  int bn = blk >> 2;
  int parity = (blk >> 1) & 1;
  int h = blk & 1;
  int b = bn >> 3, n = bn & 7;
  const float* xb = x + (size_t)b * (T_ * N_) + n;

  float v0 = xb[tid * 8];
  float v1 = xb[(tid + 512) * 8];
  float v2 = xb[(tid + 1024) * 8];
  float v3 = xb[(tid + 1536) * 8];
  float ea = v0 + v2, eb = v1 + v3;       // e[tid], e[tid+512]
  // Nyquist partial: (-1)^t e_t; t=tid and tid+512 share parity
  float sgn = (tid & 1) ? -(ea + eb) : (ea + eb);
#pragma unroll
  for (int off = 32; off > 0; off >>= 1) sgn += __shfl_down(sgn, off);
  if ((tid & 63) == 0) swav[tid >> 6] = sgn;

  if (parity == 0) {
    float* ya = (float*)ybuf;
    ya[tid] = ea;
    ya[tid + 512] = eb;
  } else {
    float oa = v0 - v2, ob = v1 - v3;
    float ca, sa, cb, sb;
    sincosf((float)tid * NEG_W0, &sa, &ca);
    sincosf((float)(tid + 512) * NEG_W0, &sb, &cb);
    ybuf[tid] = make_float2(oa * ca, oa * sa);
    ybuf[tid + 512] = make_float2(ob * cb, ob * sb);
  }
  __syncthreads();

  // ---- stage 1: thread (t0a=tid>>5 in [0,16), m0=tid&31) computes A for
  //      t0a and t0a+16 sharing one Chebyshev twiddle chain ----
  int m0 = tid & 31, t0a = tid >> 5;
  float d1 = (float)m0 * NEG_W32;
  float K1 = 2.0f * cosf(d1);
  float c = 1.f, s = 0.f, cp, sp;
  sincosf(-d1, &sp, &cp);
  float ar0 = 0.f, ai0 = 0.f, ar1 = 0.f, ai1 = 0.f;
  if (parity == 0) {
    const float* ya = (const float*)ybuf;
#pragma unroll 8
    for (int t1 = 0; t1 < 32; ++t1) {
      float y0 = ya[t1 * 32 + t0a];
      float y1 = ya[t1 * 32 + t0a + 16];
      ar0 = fmaf(y0, c, ar0); ai0 = fmaf(y0, s, ai0);
      ar1 = fmaf(y1, c, ar1); ai1 = fmaf(y1, s, ai1);
      float nc = fmaf(K1, c, -cp), ns = fmaf(K1, s, -sp);
      cp = c; sp = s; c = nc; s = ns;
    }
  } else {
#pragma unroll 8
    for (int t1 = 0; t1 < 32; ++t1) {
      float2 y0 = ybuf[t1 * 32 + t0a];
      float2 y1 = ybuf[t1 * 32 + t0a + 16];
      ar0 = fmaf(y0.x, c, fmaf(-y0.y, s, ar0));
      ai0 = fmaf(y0.x, s, fmaf(y0.y, c, ai0));
      ar1 = fmaf(y1.x, c, fmaf(-y1.y, s, ar1));
      ai1 = fmaf(y1.x, s, fmaf(y1.y, c, ai1));
      float nc = fmaf(K1, c, -cp), ns = fmaf(K1, s, -sp);
      cp = c; sp = s; c = nc; s = ns;
    }
  }
  {
    float ct, st;
    sincosf((float)(t0a * m0) * NEG_W1024, &st, &ct);
    Bl[t0a * 32 + m0] =
        make_float2(ar0 * ct - ai0 * st, fmaf(ar0, st, ai0 * ct));
    sincosf((float)((t0a + 16) * m0) * NEG_W1024, &st, &ct);
    Bl[(t0a + 16) * 32 + m0] =
        make_float2(ar1 * ct - ai1 * st, fmaf(ar1, st, ai1 * ct));
  }
  __syncthreads();

  // ---- stage 2: this block's m1 in [h*8, h*8+8); 2 threads per bin over
  //      t0-halves ----
  int m02 = tid & 31;
  int m1 = h * 8 + ((tid >> 5) & 7);
  int th = tid >> 8;                      // 0/1: t0 in [0,16)/[16,32)
  float d2 = (float)m1 * NEG_W32;
  float K2 = 2.0f * cosf(d2);
  int t0s = th * 16;
  float c2, s2, c2p, s2p;
  sincosf((float)t0s * d2, &s2, &c2);
  sincosf((float)(t0s - 1) * d2, &s2p, &c2p);
  float yr = 0.f, yi = 0.f;
#pragma unroll 8
  for (int jj = 0; jj < 16; ++jj) {
    float2 bv = Bl[(t0s + jj) * 32 + m02];
    yr = fmaf(bv.x, c2, fmaf(-bv.y, s2, yr));
    yi = fmaf(bv.x, s2, fmaf(bv.y, c2, yi));
    float nc = fmaf(K2, c2, -c2p), ns = fmaf(K2, s2, -s2p);
    c2p = c2; s2p = s2; c2 = nc; s2 = ns;
  }
  part[tid] = make_float2(yr, yi);
  __syncthreads();
  if (tid < 256) {
    float2 pa = part[tid], pb = part[tid + 256];
    float rr = pa.x + pb.x, ii = pa.y + pb.y;
    float P = fmaf(rr, rr, ii * ii);
#pragma unroll
    for (int off = 32; off > 0; off >>= 1) P = fmaxf(P, __shfl_down(P, off));
    if ((tid & 63) == 0) pwav[tid >> 6] = P;
  }
  __syncthreads();
  if (tid < 64) {
    float mxv = (tid < 4) ? pwav[tid] : 0.f;
    float svv = (tid < 8) ? swav[tid] : 0.f;
#pragma unroll
    for (int off = 4; off > 0; off >>= 1) {
      mxv = fmaxf(mxv, __shfl_down(mxv, off));
      svv += __shfl_down(svv, off);
    }
    if (tid == 0) {
      pmax[blk] = mxv;                    // unconditional plain store
      if (parity == 0) nyqS[bn] = svv;    // both h-blocks store same value
    }
  }
}

// ---- main (R11 structure, best measured): MFMA (conv slots 0..23 +
// temporal 24..31) -> LDS repack -> 4 x 8 KB sequential store rounds.
// Block = one 16-row t-tile x 512 d x 4 batches; grid 512.
__global__ __launch_bounds__(512, 4) void main_kernel(
    const short* __restrict__ amat, const short* __restrict__ xbf,
    const short* __restrict__ cnt, const float* __restrict__ tab,
    const float* __restrict__ pmax, const float* __restrict__ nyqS,
    float* __restrict__ out) {
  __shared__ __align__(16) float lds[16 * LPAD];
  int tid = threadIdx.x;
  int lane = tid & 63;
  int w = tid >> 6;            // wave -> d in [w*64, w*64+64)
  int c = lane & 15;           // t-col / A d-row
  int g = lane >> 4;           // k-slot group / C d-subgroup
  int blk = blockIdx.x;
  int ttile = blk >> 2;
  int bg = blk & 3;            // batches bg*4 .. bg*4+3
  int t0 = ttile * 16;

  // w1/w0 for the 4 batches (wave-uniform scalar loads, L2-hot)
  float w1v[4], w0v[4];
#pragma unroll
  for (int j = 0; j < 4; ++j) {
    int b = bg * 4 + j;
    int m = 0;
#pragma unroll
    for (int nn = 0; nn < 8; ++nn) {
      int bn = b * 8 + nn;
      float mx = fmaxf(fmaxf(pmax[4 * bn], pmax[4 * bn + 1]),
                       fmaxf(pmax[4 * bn + 2], pmax[4 * bn + 3]));
      float S = nyqS[bn];
      if (S * S > mx) ++m;
    }
    w1v[j] = (float)(8 - m) * 0.125f;
    w0v[j] = (float)m * 0.125f;
  }

  bf16x8 afrag[DTW];
  f32x4 fet[DTW];
#pragma unroll
  for (int q = 0; q < DTW; ++q) {
    int d0 = (w * DTW + q) * 16;
    afrag[q] = *(const bf16x8*)(amat + (size_t)(d0 + c) * 32 + g * 8);
    fet[q] = *(const f32x4*)(tab + (size_t)(t0 + c) * D_ + d0 + g * 4);
  }

  const f32x4 zac = {0.f, 0.f, 0.f, 0.f};
#pragma unroll
  for (int j = 0; j < 4; ++j) {
    int b = bg * 4 + j;
    bf16x8 bfrag;
    if (g < 3) {
      int row = (t0 + c + g - 1) & (T_ - 1);    // circular pad
      bfrag = *(const bf16x8*)(xbf + ((size_t)b * T_ + row) * 8);
    } else {
      bfrag = *(const bf16x8*)(cnt + ((size_t)b * T_ + t0 + c) * 8);
    }
    float w1 = w1v[j], w0 = w0v[j];
#pragma unroll
    for (int q = 0; q < DTW; ++q) {
      f32x4 acc = __builtin_amdgcn_mfma_f32_16x16x32_bf16(
          afrag[q], bfrag, zac, 0, 0, 0);
      f32x4 ov;
      ov[0] = fmaf(w1, fet[q][0], acc[0]);
      ov[1] = fmaf(w1, fet[q][1], acc[1]) + w0;
      ov[2] = fmaf(w1, fet[q][2], acc[2]);
      ov[3] = fmaf(w1, fet[q][3], acc[3]) + w0;
      int d0 = (w * DTW + q) * 16;
      *(f32x4*)(lds + c * LPAD + d0 + g * 4) = ov;
    }
    __syncthreads();
    // stream the 16x512 tile out as 4 x 8KB perfectly sequential rounds
    float* obase = out + ((size_t)b * T_ + t0) * D_;
#pragma unroll
    for (int r = 0; r < 4; ++r) {
      int e = r * 2048 + tid * 4;               // element offset in tile
      int trow = e >> 9, col = e & 511;
      f32x4 v = *(const f32x4*)(lds + trow * LPAD + col);
      *(f32x4*)(obase + e) = v;
    }
    __syncthreads();                            // before next batch reuses lds
  }
}

extern "C" void kernel_launch(void* const* d_in, const int* in_sizes, int n_in,
                              void* d_out, int out_size, void* d_ws, size_t ws_size,
                              hipStream_t stream) {
  const float* x = (const float*)d_in[0];
  const int* xmark = (const int*)d_in[1];
  const float* convw = (const float*)d_in[2];
  float* out = (float*)d_out;

  char* ws = (char*)d_ws;
  float* pmax = (float*)ws;                            // 512 f
  float* nyqS = pmax + 512;                            // 128 f
  float* tab = (float*)(ws + 4096);                    // 4 MB FET
  short* amat = (short*)(ws + 4096 + 4194304);         // 32 KB
  short* xbf = (short*)(ws + 4096 + 4194304 + 32768);  // 512 KB
  short* cnt = (short*)(ws + 4096 + 4194304 + 32768 + 524288);  // 512 KB

  prep_kernel<<<609, 512, 0, stream>>>(x, xmark, convw, pmax, nyqS, tab,
                                       amat, xbf, cnt);
  main_kernel<<<(T_ / 16) * (B_ / 4), 512, 0, stream>>>(amat, xbf, cnt, tab,
                                                        pmax, nyqS, out);
}

// Round 15
// 28.886 us; speedup vs baseline: 1.0896x; 1.0328x over previous
//
#include <hip/hip_runtime.h>
#include <math.h>

#define B_ 16
#define T_ 2048
#define N_ 8
#define D_ 512
#define DTW 4           // d-tiles (of 16) per wave
#define LPAD 520        // LDS row pitch (words)

// -2*pi/2048
#define NEG_W0 (-3.0679615757712823e-3f)
// -2*pi/32
#define NEG_W32 (-0.19634954084936207f)
// -2*pi/1024
#define NEG_W1024 (-6.1359231515425647e-3f)
// -2*ln(10000)/512
#define NEG_LDIV (-0.035977892078031555f)

typedef __attribute__((ext_vector_type(8))) short bf16x8;
typedef __attribute__((ext_vector_type(4))) float f32x4;

// fp32 -> bf16 (round-to-nearest-even)
static __device__ __forceinline__ short f2bf(float f) {
  unsigned int u = __float_as_uint(f);
  unsigned int r = u + 0x7FFFu + ((u >> 16) & 1u);
  return (short)(r >> 16);
}

// ws layout (byte offsets): [0,4096) pmax[256]+nyqS[128];
// [4K,4K+4M) FET tab f32[2048][512]; amat bf16[512][32] (32 KB);
// xbf bf16[16][2048][8] (512 KB); cnt bf16[16][2048][8] (512 KB).
// All rewritten unconditionally every call (no init/protocol hazards).

// ---- prep: 417 blocks x 1024 thr (R11's exact form — best measured).
//  blk 0..255 : folded radix-32 FFT per (bn,parity) -> pmax/nyqS
//  blk 256..287: xbf (x cast to bf16 rows) + cnt (mark-count bf16x8 rows)
//  blk 288    : amat (A-matrix: conv slots 0..23, temporal 24..30, 31=0)
//  blk 289..416: FET tabgen, 2 float4 per thread (128 blocks, exact cover)
__global__ __launch_bounds__(1024) void prep_kernel(
    const float* __restrict__ x, const int* __restrict__ xmark,
    const float* __restrict__ convw, float* __restrict__ pmax,
    float* __restrict__ nyqS, float* __restrict__ tab,
    short* __restrict__ amat, short* __restrict__ xbf,
    short* __restrict__ cnt) {
  int tid = threadIdx.x;
  int blk = blockIdx.x;

  if (blk >= 256) {
    int j = blk - 256;
    if (j < 32) {                         // ---- xbf + cnt rows ----
      int r = j * 1024 + tid;             // r = b*T + t, 0..32767
      const float4* xr = (const float4*)(x + (size_t)r * 8);
      float4 lo = xr[0], hi = xr[1];
      bf16x8 v;
      v[0] = f2bf(lo.x); v[1] = f2bf(lo.y); v[2] = f2bf(lo.z); v[3] = f2bf(lo.w);
      v[4] = f2bf(hi.x); v[5] = f2bf(hi.y); v[6] = f2bf(hi.z); v[7] = f2bf(hi.w);
      *(bf16x8*)(xbf + (size_t)r * 8) = v;
      int4 mk = *(const int4*)(xmark + (size_t)r * 4);
      bf16x8 cv;
#pragma unroll
      for (int p = 0; p < 8; ++p) {
        int cc = (mk.x == p) + (mk.y == p) + (mk.z == p) + (mk.w == p);
        cv[p] = f2bf((float)cc);
      }
      *(bf16x8*)(cnt + (size_t)r * 8) = cv;
    } else if (j == 32) {                 // ---- amat builder ----
      if (tid < 512) {
        int d = tid;
        short row[32];
#pragma unroll
        for (int kk = 0; kk < 24; ++kk) {
          int g = kk >> 3, n = kk & 7;    // A[d][g*8+n] = W[d][n][k=g]
          row[kk] = f2bf(convw[d * 24 + n * 3 + g]);
        }
        float divv = expf((float)(d >> 1) * NEG_LDIV);
        float s1, c1;
        sincosf(divv, &s1, &c1);
        int odd = d & 1;
        row[24] = f2bf(odd ? 1.f : 0.f);
        float ps = s1, pc = c1;
        row[25] = f2bf(odd ? pc : ps);
#pragma unroll
        for (int p = 2; p < 7; ++p) {
          float ns = fmaf(ps, c1, pc * s1);
          float nc = fmaf(pc, c1, -ps * s1);
          ps = ns; pc = nc;
          row[24 + p] = f2bf(odd ? pc : ps);
        }
        row[31] = 0;                      // marks < 7
#pragma unroll
        for (int q = 0; q < 4; ++q)
          *(bf16x8*)(amat + d * 32 + q * 8) = *(bf16x8*)&row[q * 8];
      }
    } else {                              // ---- FET tabgen (2 f4/thread) ----
      int base = (j - 33) * 2048 + tid * 2;
#pragma unroll
      for (int u = 0; u < 2; ++u) {
        int idx = base + u;
        int t = idx >> 7;
        int d4 = idx & 127;
        float ft = (float)t;
        float dv0 = expf((float)(d4 * 2) * NEG_LDIV);
        float dv1 = expf((float)(d4 * 2 + 1) * NEG_LDIV);
        f32x4 v;
        float s0, c0, s1, c1;
        sincosf(ft * dv0, &s0, &c0);
        sincosf(ft * dv1, &s1, &c1);
        v[0] = s0; v[1] = c0; v[2] = s1; v[3] = c1;
        *(f32x4*)(tab + (size_t)idx * 4) = v;
      }
    }
    return;
  }

  // ---- folded radix-32 FFT (validated R4..R14) ----
  __shared__ __align__(16) float2 ybuf[1024];
  __shared__ __align__(16) float2 Bl[1024];
  __shared__ __align__(16) float2 part[1024];
  __shared__ float swav[16];
  __shared__ float pwav[8];
  int bn = blk >> 1, parity = blk & 1;
  int b = bn >> 3, n = bn & 7;
  const float* xb = x + (size_t)b * (T_ * N_) + n;

  float va = xb[tid * 8];
  float vb = xb[(tid + 1024) * 8];
  float ea = va + vb;
  float sgn = (tid & 1) ? -ea : ea;       // Nyquist partial (-1)^t e_t
#pragma unroll
  for (int off = 32; off > 0; off >>= 1) sgn += __shfl_down(sgn, off);
  if ((tid & 63) == 0) swav[tid >> 6] = sgn;

  if (parity == 0) {
    ((float*)ybuf)[tid] = ea;
  } else {
    float o = va - vb;
    float c0, s0;
    sincosf((float)tid * NEG_W0, &s0, &c0);
    ybuf[tid] = make_float2(o * c0, o * s0);
  }
  __syncthreads();

  int m0 = tid & 31, t0 = tid >> 5;
  float d1 = (float)m0 * NEG_W32;
  float K1 = 2.0f * cosf(d1);
  float c = 1.f, s = 0.f, cp, sp;
  sincosf(-d1, &sp, &cp);
  float ar = 0.f, ai = 0.f;
  if (parity == 0) {
    const float* ya = (const float*)ybuf;
#pragma unroll 8
    for (int t1 = 0; t1 < 32; ++t1) {
      float y = ya[t1 * 32 + t0];
      ar = fmaf(y, c, ar); ai = fmaf(y, s, ai);
      float nc = fmaf(K1, c, -cp), ns = fmaf(K1, s, -sp);
      cp = c; sp = s; c = nc; s = ns;
    }
  } else {
#pragma unroll 8
    for (int t1 = 0; t1 < 32; ++t1) {
      float2 y = ybuf[t1 * 32 + t0];
      ar = fmaf(y.x, c, fmaf(-y.y, s, ar));
      ai = fmaf(y.x, s, fmaf(y.y, c, ai));
      float nc = fmaf(K1, c, -cp), ns = fmaf(K1, s, -sp);
      cp = c; sp = s; c = nc; s = ns;
    }
  }
  {
    float ct, st;
    sincosf((float)(t0 * m0) * NEG_W1024, &st, &ct);
    Bl[t0 * 32 + m0] = make_float2(ar * ct - ai * st, fmaf(ar, st, ai * ct));
  }
  __syncthreads();

  int m02 = tid & 31;
  int m1 = (tid >> 5) & 15;
  int h = tid >> 9;
  float d2 = (float)m1 * NEG_W32;
  float K2 = 2.0f * cosf(d2);
  int t0s = h * 16;
  float c2, s2, c2p, s2p;
  sincosf((float)t0s * d2, &s2, &c2);
  sincosf((float)(t0s - 1) * d2, &s2p, &c2p);
  float yr = 0.f, yi = 0.f;
#pragma unroll 8
  for (int jj = 0; jj < 16; ++jj) {
    float2 bv = Bl[(t0s + jj) * 32 + m02];
    yr = fmaf(bv.x, c2, fmaf(-bv.y, s2, yr));
    yi = fmaf(bv.x, s2, fmaf(bv.y, c2, yi));
    float nc = fmaf(K2, c2, -c2p), ns = fmaf(K2, s2, -s2p);
    c2p = c2; s2p = s2; c2 = nc; s2 = ns;
  }
  part[tid] = make_float2(yr, yi);
  __syncthreads();
  if (tid < 512) {
    float2 pa = part[tid], pb = part[tid + 512];
    float rr = pa.x + pb.x, ii = pa.y + pb.y;
    float P = fmaf(rr, rr, ii * ii);
#pragma unroll
    for (int off = 32; off > 0; off >>= 1) P = fmaxf(P, __shfl_down(P, off));
    if ((tid & 63) == 0) pwav[tid >> 6] = P;
  }
  __syncthreads();
  if (tid < 64) {
    float mxv = (tid < 8) ? pwav[tid] : 0.f;
    float svv = (tid < 16) ? swav[tid] : 0.f;
#pragma unroll
    for (int off = 8; off > 0; off >>= 1) {
      mxv = fmaxf(mxv, __shfl_down(mxv, off));
      svv += __shfl_down(svv, off);
    }
    if (tid == 0) {
      pmax[blk] = mxv;                    // unconditional plain store
      if (parity == 0) nyqS[bn] = svv;
    }
  }
}

// ---- main: MFMA (conv slots 0..23 + temporal 24..31) -> LDS repack ->
// 4 x 8 KB sequential store rounds. Block = 16-row t-tile x 512 d x
// 2 batches; grid 1024 -> 3 blocks/CU resident (+1 queued), so the store
// pipe stays fed while any one block is in its compute phase.
// ttile = blk&127, bg = blk>>7: co-t-tile blocks 128 apart -> same XCD
// (FET tile L2-shared); consecutive blocks stream adjacent FET rows.
__global__ __launch_bounds__(512, 6) void main_kernel(
    const short* __restrict__ amat, const short* __restrict__ xbf,
    const short* __restrict__ cnt, const float* __restrict__ tab,
    const float* __restrict__ pmax, const float* __restrict__ nyqS,
    float* __restrict__ out) {
  __shared__ __align__(16) float lds[16 * LPAD];
  int tid = threadIdx.x;
  int lane = tid & 63;
  int w = tid >> 6;            // wave -> d in [w*64, w*64+64)
  int c = lane & 15;           // t-col / A d-row
  int g = lane >> 4;           // k-slot group / C d-subgroup
  int blk = blockIdx.x;
  int ttile = blk & 127;
  int bg = blk >> 7;           // batches bg*2, bg*2+1
  int t0 = ttile * 16;

  // w1/w0 for the 2 batches (wave-uniform scalar loads, L2-hot)
  float w1v[2], w0v[2];
#pragma unroll
  for (int j = 0; j < 2; ++j) {
    int b = bg * 2 + j;
    int m = 0;
#pragma unroll
    for (int nn = 0; nn < 8; ++nn) {
      int bn = b * 8 + nn;
      float mx = fmaxf(pmax[2 * bn], pmax[2 * bn + 1]);
      float S = nyqS[bn];
      if (S * S > mx) ++m;
    }
    w1v[j] = (float)(8 - m) * 0.125f;
    w0v[j] = (float)m * 0.125f;
  }

  bf16x8 afrag[DTW];
  f32x4 fet[DTW];
#pragma unroll
  for (int q = 0; q < DTW; ++q) {
    int d0 = (w * DTW + q) * 16;
    afrag[q] = *(const bf16x8*)(amat + (size_t)(d0 + c) * 32 + g * 8);
    fet[q] = *(const f32x4*)(tab + (size_t)(t0 + c) * D_ + d0 + g * 4);
  }

  const f32x4 zac = {0.f, 0.f, 0.f, 0.f};
#pragma unroll
  for (int j = 0; j < 2; ++j) {
    int b = bg * 2 + j;
    bf16x8 bfrag;
    if (g < 3) {
      int row = (t0 + c + g - 1) & (T_ - 1);    // circular pad
      bfrag = *(const bf16x8*)(xbf + ((size_t)b * T_ + row) * 8);
    } else {
      bfrag = *(const bf16x8*)(cnt + ((size_t)b * T_ + t0 + c) * 8);
    }
    float w1 = w1v[j], w0 = w0v[j];
#pragma unroll
    for (int q = 0; q < DTW; ++q) {
      f32x4 acc = __builtin_amdgcn_mfma_f32_16x16x32_bf16(
          afrag[q], bfrag, zac, 0, 0, 0);
      f32x4 ov;
      ov[0] = fmaf(w1, fet[q][0], acc[0]);
      ov[1] = fmaf(w1, fet[q][1], acc[1]) + w0;
      ov[2] = fmaf(w1, fet[q][2], acc[2]);
      ov[3] = fmaf(w1, fet[q][3], acc[3]) + w0;
      int d0 = (w * DTW + q) * 16;
      *(f32x4*)(lds + c * LPAD + d0 + g * 4) = ov;
    }
    __syncthreads();
    // stream the 16x512 tile out as 4 x 8KB perfectly sequential rounds
    float* obase = out + ((size_t)b * T_ + t0) * D_;
#pragma unroll
    for (int r = 0; r < 4; ++r) {
      int e = r * 2048 + tid * 4;               // element offset in tile
      int trow = e >> 9, col = e & 511;
      f32x4 v = *(const f32x4*)(lds + trow * LPAD + col);
      *(f32x4*)(obase + e) = v;
    }
    if (j == 0) __syncthreads();                // last iter: no LDS reuse
  }
}

extern "C" void kernel_launch(void* const* d_in, const int* in_sizes, int n_in,
                              void* d_out, int out_size, void* d_ws, size_t ws_size,
                              hipStream_t stream) {
  const float* x = (const float*)d_in[0];
  const int* xmark = (const int*)d_in[1];
  const float* convw = (const float*)d_in[2];
  float* out = (float*)d_out;

  char* ws = (char*)d_ws;
  float* pmax = (float*)ws;                            // 256 f
  float* nyqS = pmax + 256;                            // 128 f
  float* tab = (float*)(ws + 4096);                    // 4 MB FET
  short* amat = (short*)(ws + 4096 + 4194304);         // 32 KB
  short* xbf = (short*)(ws + 4096 + 4194304 + 32768);  // 512 KB
  short* cnt = (short*)(ws + 4096 + 4194304 + 32768 + 524288);  // 512 KB

  prep_kernel<<<417, 1024, 0, stream>>>(x, xmark, convw, pmax, nyqS, tab,
                                        amat, xbf, cnt);
  main_kernel<<<(T_ / 16) * (B_ / 2), 512, 0, stream>>>(amat, xbf, cnt, tab,
                                                        pmax, nyqS, out);
}